// Round 1
// baseline (111.985 us; speedup 1.0000x reference)
//
#include <hip/hip_runtime.h>

// Fused: out = ALPHA*x - ALPHA*x^3 + BETA*(N+S+W+E - 4*x), replication-padded.
// Shape: (16, 1, 1024, 1024) fp32. Memory-bound: ~134 MB ideal HBM -> ~21 us floor.
//
// R1-R2 (prev session): XCD-band swizzle so N/S re-reads hit the local 4 MiB L2;
// nontemporal stores (output never re-read). Landed ~25 us kernel time.
// R3 (this round): register sliding window. One block = one 8-row strip of one
// image (1024 % 8 == 0, strips never straddle images). Each thread holds n/c/s
// float4s in registers and slides down the strip: every row is loaded ONCE per
// block (vs 3x in the row-per-block version), halo rows are shared with the
// adjacent co-resident strip on the same XCD (L2 hit). VMEM per output quad
// drops 6 -> ~3.4 and address math amortizes to two pointer bumps per row.
// Grid = 2048 blocks = exactly 8 blocks/CU * 256 CU, fully resident.

#define ALPHA 400.0f
#define BETA  10000.0f

typedef float vfloat4 __attribute__((ext_vector_type(4)));

__global__ __launch_bounds__(256) void stencil_kernel(const float* __restrict__ x,
                                                      float* __restrict__ out) {
    constexpr int W = 1024;
    constexpr int H = 1024;
    constexpr int R = 8;          // rows per block (divides H)
    constexpr int NUM_XCD = 8;

    // XCD swizzle: dispatcher assigns block b -> XCD (b % 8); remap so each
    // XCD processes a contiguous band of strips in order (2048 % 8 == 0 ->
    // bijective). Adjacent strips (sharing halo rows) land on the same XCD.
    const int band  = gridDim.x / NUM_XCD;                      // strips per XCD
    const int strip = (blockIdx.x & (NUM_XCD - 1)) * band + (blockIdx.x >> 3);

    const int row0 = strip * R;                                 // global row
    const int y0   = row0 & (H - 1);                            // row within image
    const int x4   = threadIdx.x << 2;                          // 0..1020

    const size_t base = (size_t)row0 * W + x4;
    const float* pc = x + base;        // this thread's 4-col group, current row
    float*       po = out + base;

    const bool left  = (x4 == 0);
    const bool right = (x4 == W - 4);

    // Prime the window: n (replication-clamped at image top) and c.
    vfloat4 n = *(const vfloat4*)(pc - ((y0 == 0) ? 0 : W));
    vfloat4 c = *(const vfloat4*)pc;

    #pragma unroll
    for (int r = 0; r < R; ++r) {
        const int y = y0 + r;
        // south row, replication-clamped at image bottom (only fires when
        // y0 == H-R and r == R-1, since strips are image-aligned)
        const vfloat4 s = *(const vfloat4*)(pc + ((y == H - 1) ? 0 : W));

        // west/east scalars: same cache lines as neighbor threads' c-loads
        // (loaded as s one iteration ago -> L1 hit), clamped at image edge.
        const float wv = left  ? c.x : pc[-1];
        const float ev = right ? c.w : pc[4];

        vfloat4 o;
        o.x = ALPHA * c.x - ALPHA * (c.x * c.x * c.x) + BETA * (n.x + s.x + wv  + c.y - 4.0f * c.x);
        o.y = ALPHA * c.y - ALPHA * (c.y * c.y * c.y) + BETA * (n.y + s.y + c.x + c.z - 4.0f * c.y);
        o.z = ALPHA * c.z - ALPHA * (c.z * c.z * c.z) + BETA * (n.z + s.z + c.y + c.w - 4.0f * c.z);
        o.w = ALPHA * c.w - ALPHA * (c.w * c.w * c.w) + BETA * (n.w + s.w + c.z + ev  - 4.0f * c.w);

        __builtin_nontemporal_store(o, (vfloat4*)po);

        n = c;
        c = s;
        pc += W;
        po += W;
    }
}

extern "C" void kernel_launch(void* const* d_in, const int* in_sizes, int n_in,
                              void* d_out, int out_size, void* d_ws, size_t ws_size,
                              hipStream_t stream) {
    const float* x0 = (const float*)d_in[0];
    float* out = (float*)d_out;
    // out_size = 16*1024*1024 elements -> 16384 rows -> 2048 strips of 8 rows
    constexpr int R = 8;
    const int rows = out_size / 1024;
    const int grid = rows / R;
    stencil_kernel<<<grid, 256, 0, stream>>>(x0, out);
}